// Round 14
// baseline (262.512 us; speedup 1.0000x reference)
//
#include <hip/hip_runtime.h>

typedef _Float16 f16;
typedef f16 f16x2 __attribute__((ext_vector_type(2)));
typedef f16 f16x4 __attribute__((ext_vector_type(4)));
typedef f16 f16x8 __attribute__((ext_vector_type(8)));
typedef float f32x4 __attribute__((ext_vector_type(4)));
typedef float f32x16 __attribute__((ext_vector_type(16)));
typedef unsigned int u32;
typedef u32 u32x2 __attribute__((ext_vector_type(2)));
typedef u32 u32x4 __attribute__((ext_vector_type(4)));

#define MFMA32(a, b, c) __builtin_amdgcn_mfma_f32_32x32x16_f16((a), (b), (c), 0, 0, 0)

__device__ __forceinline__ u32 pk2(float a, float b) {
    return __builtin_bit_cast(u32, __builtin_amdgcn_cvt_pkrtz(a, b));
}
__device__ __forceinline__ f16x4 lo4(f16x8 v) { return __builtin_shufflevector(v, v, 0, 1, 2, 3); }
__device__ __forceinline__ f16x4 hi4(f16x8 v) { return __builtin_shufflevector(v, v, 4, 5, 6, 7); }

// C-frag (rows in regs, col on lanes) -> A/B-frag (same lane, 8 consecutive rows as elems).
__device__ __forceinline__ f16x8 xfrm(f32x16 v, int rb) {
    u32 a0 = pk2(v[rb + 0], v[rb + 1]);
    u32 a1 = pk2(v[rb + 2], v[rb + 3]);
    u32 b0 = pk2(v[rb + 4], v[rb + 5]);
    u32 b1 = pk2(v[rb + 6], v[rb + 7]);
    u32x2 r0 = __builtin_amdgcn_permlane32_swap(a0, b0, false, false);
    u32x2 r1 = __builtin_amdgcn_permlane32_swap(a1, b1, false, false);
    u32x4 aw = {r0.x, r1.x, r0.y, r1.y};
    return __builtin_bit_cast(f16x8, aw);
}
__device__ __forceinline__ f16x8 add8(f16x8 a, f16x8 b) {
    f16x8 r;
#pragma unroll
    for (int j = 0; j < 8; ++j) r[j] = a[j] + b[j];
    return r;
}

// disjoint-LDS attention kernel regions -------------------------------------
#define AD_OFF_Y 65536
#define AD_OFF_V 98304
#define AD_LDS   163840

// per-pass Wf stride in f16: 32768 W + 128 bias (bq f16[64], bk f16[64])
#define WSTRIDE 32896

// =====================================================================================
// repack: x fp32 [B,C,H,W] -> Xall f16 [b][n2=(i2,j2)][n1=(i1,j1)][c]
// =====================================================================================
__global__ __launch_bounds__(512) void repack_kernel(const float* __restrict__ x,
                                                     f16* __restrict__ Xall) {
    __shared__ f16 XT[128 * 264];     // [c][w], padded
    const int tid = threadIdx.x, g = blockIdx.x;
    const int b = g >> 8, i1 = (g >> 4) & 15, i2 = g & 15;
    const int h = i1 * 16 + i2;
    {
        const int c = tid >> 2, wq = (tid & 3) * 64;
        const float* src = x + (((size_t)b * 128 + c) * 256 + h) * 256 + wq;
        f16* dst = XT + c * 264 + wq;
#pragma unroll
        for (int i = 0; i < 16; ++i) {
            f32x4 v = *(const f32x4*)(src + i * 4);
            f16x4 o = {(f16)v[0], (f16)v[1], (f16)v[2], (f16)v[3]};
            *(f16x4*)(dst + i * 4) = o;
        }
    }
    __syncthreads();
    {
        const int w = tid >> 1, ch = (tid & 1) * 64;   // w = j1*16 + j2
        const int j1 = w >> 4, j2 = w & 15;
        f16* dst = Xall + (((size_t)b * 256 + i2 * 16 + j2) * 256 + i1 * 16 + j1) * 128 + ch;
#pragma unroll
        for (int i = 0; i < 8; ++i) {
            f16x8 v;
#pragma unroll
            for (int j = 0; j < 8; ++j) v[j] = XT[(ch + i * 8 + j) * 264 + w];
            *(f16x8*)(dst + i * 8) = v;
        }
    }
}

// =====================================================================================
// weight conversion fp32 -> f16 (fragment-linear + f16 bias tail) + gstats zeroing
// =====================================================================================
__global__ void wconv_kernel(const float* __restrict__ w1x, const float* __restrict__ w1y,
                             const float* __restrict__ w1o, const float* __restrict__ b1x,
                             const float* __restrict__ b1y, const float* __restrict__ w2x,
                             const float* __restrict__ w2y, const float* __restrict__ w2o,
                             const float* __restrict__ b2x, const float* __restrict__ b2y,
                             f16* __restrict__ Wf, float* __restrict__ gstats) {
    int i = blockIdx.x * 256 + threadIdx.x;      // 66304 total
    if (i < 65536) {
        int p = i >> 15, idx = i & 32767;
        int j = idx & 7, lane = (idx >> 3) & 63, ks = (idx >> 9) & 7, r = idx >> 12;
        int row = r * 32 + (lane & 31);
        int c = ks * 16 + (lane >> 5) * 8 + j;
        const float* s;
        if (p == 0) s = (row < 128) ? w1o + row * 128 : (row < 192) ? w1x + (row - 128) * 128
                                                                   : w1y + (row - 192) * 128;
        else        s = (row < 128) ? w2o + row * 128 : (row < 192) ? w2x + (row - 128) * 128
                                                                   : w2y + (row - 192) * 128;
        Wf[p * WSTRIDE + idx] = (f16)s[c];
    } else if (i < 65792) {
        int idx2 = i - 65536;                    // 0..255
        int p = idx2 >> 7, r = idx2 & 127;
        const float* bsrc = (p == 0) ? ((r < 64) ? b1x : b1y) : ((r < 64) ? b2x : b2y);
        Wf[p * WSTRIDE + 32768 + r] = (f16)bsrc[r & 63];
    } else {
        gstats[i - 65792] = 0.f;                 // [2][256] stats cleared
    }
}

// =====================================================================================
// attd: disjoint-LDS fused attention, both passes.
//   out = softmax(theta psi) @ (X Wo^T + bo)
// W(64K) + Yf(32K) + Vf(64K) disjoint; 2 heavy barriers; register BN-stats.
// PASS2 computes BN1 (a,b) in-register from raw gstats (no separate bnfix kernel).
// =====================================================================================
template <int PASS>
__global__ __launch_bounds__(512, 2) void attd_kernel(
    const f16* __restrict__ Xin, const f16* __restrict__ Wf, const float* __restrict__ bo,
    const float* __restrict__ gin, const float* __restrict__ gamma,
    const float* __restrict__ beta, f16* __restrict__ Uout, float* __restrict__ gstats,
    int t_stride, int s_stride) {
    __shared__ __align__(16) char smem[AD_LDS];
    const int tid = threadIdx.x;
    const int w = tid >> 6, l = tid & 63, hl = l >> 5, l31 = l & 31;
    const int g = blockIdx.x, R0 = w * 32;

    const f16* bfp = Wf + 32768;
    f16x8 bqf[4], bkf[4];
#pragma unroll
    for (int ks = 0; ks < 4; ++ks) {
        bqf[ks] = *(const f16x8*)(bfp + ks * 16 + hl * 8);
        bkf[ks] = *(const f16x8*)(bfp + 64 + ks * 16 + hl * 8);
    }
    float bov[4];
#pragma unroll
    for (int ct = 0; ct < 4; ++ct) bov[ct] = bo[ct * 32 + l31];

    // ---- prologue: W -> LDS, X -> afr (loads overlap); PASS2: BN1+ReLU in-register ----
    f16x8 afr[8];
    {
        f16x8 wv[8];
#pragma unroll
        for (int j = 0; j < 8; ++j)
            wv[j] = *(const f16x8*)((const char*)Wf + (j * 512 + tid) * 16);
        const f16* src = Xin + (size_t)g * 32768 + (R0 + l31) * 128 + hl * 8;
#pragma unroll
        for (int ks = 0; ks < 8; ++ks) afr[ks] = *(const f16x8*)(src + ks * 16);
        if constexpr (PASS == 2) {
            const float inv = 1.f / 262144.f;
#pragma unroll
            for (int ks = 0; ks < 8; ++ks) {
                const int c0 = ks * 16 + hl * 8;
                f32x4 m0 = *(const f32x4*)(gin + c0), m1 = *(const f32x4*)(gin + c0 + 4);
                f32x4 q0 = *(const f32x4*)(gin + 128 + c0), q1 = *(const f32x4*)(gin + 132 + c0);
                f32x4 gm0 = *(const f32x4*)(gamma + c0), gm1 = *(const f32x4*)(gamma + c0 + 4);
                f32x4 bt0 = *(const f32x4*)(beta + c0), bt1 = *(const f32x4*)(beta + c0 + 4);
                f16x8 v = afr[ks];
#pragma unroll
                for (int j = 0; j < 4; ++j) {
                    float mean = m0[j] * inv;
                    float var = q0[j] * inv - mean * mean;
                    float a = gm0[j] * rsqrtf(var + 1e-5f);
                    float b = bt0[j] - mean * a;
                    v[j] = (f16)fmaxf(a * (float)v[j] + b, 0.f);
                    mean = m1[j] * inv;
                    var = q1[j] * inv - mean * mean;
                    a = gm1[j] * rsqrtf(var + 1e-5f);
                    b = bt1[j] - mean * a;
                    v[j + 4] = (f16)fmaxf(a * (float)v[j + 4] + b, 0.f);
                }
                afr[ks] = v;
            }
        }
#pragma unroll
        for (int j = 0; j < 8; ++j)
            *(f16x8*)(smem + (j * 512 + tid) * 16) = wv[j];
    }
    __syncthreads();   // b0: W resident

    // ---- psi^T (tiles 6-7) -> Yf ----
    {
        f32x16 aP[2] = {};
#pragma unroll
        for (int ks = 0; ks < 8; ++ks)
#pragma unroll
            for (int mt = 0; mt < 2; ++mt) {
                f16x8 wk = *(const f16x8*)(smem + (((6 + mt) * 8 + ks) * 64 + l) * 16);
                aP[mt] = MFMA32(wk, afr[ks], aP[mt]);
            }
#pragma unroll
        for (int ks = 0; ks < 4; ++ks) {
            f16x8 yf = add8(xfrm(aP[ks >> 1], 8 * (ks & 1)), bkf[ks]);
            *(f16x8*)(smem + AD_OFF_Y + ((w * 4 + ks) * 64 + l) * 16) = yf;
        }
    }

    // ---- theta^T (tiles 4-5) -> tb in-register ----
    f16x8 tb[4];
    {
        f32x16 aT[2] = {};
#pragma unroll
        for (int ks = 0; ks < 8; ++ks)
#pragma unroll
            for (int mt = 0; mt < 2; ++mt) {
                f16x8 wq = *(const f16x8*)(smem + (((4 + mt) * 8 + ks) * 64 + l) * 16);
                aT[mt] = MFMA32(wq, afr[ks], aT[mt]);
            }
#pragma unroll
        for (int ks = 0; ks < 4; ++ks)
            tb[ks] = add8(xfrm(aT[ks >> 1], 8 * (ks & 1)), bqf[ks]);
    }

    // ---- V'' (tiles 0-3) -> pack -> Vf ----
    {
        f32x16 aV[4] = {};
#pragma unroll
        for (int ks = 0; ks < 8; ++ks)
#pragma unroll
            for (int ct = 0; ct < 4; ++ct) {
                f16x8 wo = *(const f16x8*)(smem + ((ct * 8 + ks) * 64 + l) * 16);
                aV[ct] = MFMA32(afr[ks], wo, aV[ct]);
            }
#pragma unroll
        for (int ct = 0; ct < 4; ++ct) {
#pragma unroll
            for (int e = 0; e < 16; ++e) aV[ct][e] += bov[ct];
#pragma unroll
            for (int ksl = 0; ksl < 2; ++ksl)
                *(f16x8*)(smem + AD_OFF_V + (((2 * w + ksl) * 4 + ct) * 64 + l) * 16) =
                    xfrm(aV[ct], 8 * ksl);
        }
    }
    __syncthreads();   // b1: Yf + Vf complete

    // ---- S^T: col t = R0+l31 on lanes, all 256 k rows in regs ----
    f32x16 s[8] = {};
    __builtin_amdgcn_s_setprio(1);
#pragma unroll
    for (int kt = 0; kt < 8; ++kt)
#pragma unroll
        for (int ks = 0; ks < 4; ++ks) {
            f16x8 ay = *(const f16x8*)(smem + AD_OFF_Y + ((kt * 4 + ks) * 64 + l) * 16);
            s[kt] = MFMA32(ay, tb[ks], s[kt]);
        }
    __builtin_amdgcn_s_setprio(0);

    // ---- softmax over k ----
    float mx = -1e30f;
#pragma unroll
    for (int kt = 0; kt < 8; ++kt) {
        float m0 = fmaxf(fmaxf(s[kt][0], s[kt][1]), fmaxf(s[kt][2], s[kt][3]));
        float m1 = fmaxf(fmaxf(s[kt][4], s[kt][5]), fmaxf(s[kt][6], s[kt][7]));
        float m2 = fmaxf(fmaxf(s[kt][8], s[kt][9]), fmaxf(s[kt][10], s[kt][11]));
        float m3 = fmaxf(fmaxf(s[kt][12], s[kt][13]), fmaxf(s[kt][14], s[kt][15]));
        mx = fmaxf(mx, fmaxf(fmaxf(m0, m1), fmaxf(m2, m3)));
    }
    mx = fmaxf(mx, __shfl_xor(mx, 32));
    float sum = 0.f;
#pragma unroll
    for (int kt = 0; kt < 8; ++kt)
#pragma unroll
        for (int e = 0; e < 16; ++e) {
            float p = __expf(s[kt][e] - mx);
            s[kt][e] = p;
            sum += p;
        }
    sum += __shfl_xor(sum, 32);
    const float rs = 1.f / sum;
#pragma unroll
    for (int kt = 0; kt < 8; ++kt)
#pragma unroll
        for (int e = 0; e < 16; ++e) s[kt][e] *= rs;

    // ---- PV: A-frags in-register (xfrm), B from Vf ----
    f32x16 o[4] = {};
#pragma unroll
    for (int kt = 0; kt < 8; ++kt)
#pragma unroll
        for (int ks2 = 0; ks2 < 2; ++ks2) {
            f16x8 ap = xfrm(s[kt], 8 * ks2);
            __builtin_amdgcn_s_setprio(1);
#pragma unroll
            for (int ct = 0; ct < 4; ++ct) {
                f16x8 bv =
                    *(const f16x8*)(smem + AD_OFF_V + (((kt * 2 + ks2) * 4 + ct) * 64 + l) * 16);
                o[ct] = MFMA32(ap, bv, o[ct]);
            }
            __builtin_amdgcn_s_setprio(0);
        }

    // ---- BN stats (registers) + stores ----
    float ssa[4], sqa[4];
#pragma unroll
    for (int ct = 0; ct < 4; ++ct) {
        float ss = 0.f, sq = 0.f;
#pragma unroll
        for (int e = 0; e < 16; ++e) {
            float v = o[ct][e];
            ss += v;
            sq += v * v;
        }
        ssa[ct] = ss + __shfl_xor(ss, 32);
        sqa[ct] = sq + __shfl_xor(sq, 32);
    }
    const size_t ub = (size_t)(g >> 8) * 8388608 + (size_t)(g & 255) * (size_t)s_stride;
#pragma unroll
    for (int r = 0; r < 16; ++r) {
        int trow = (r & 3) + 8 * (r >> 2) + 4 * hl;
        f16* rp = Uout + ub + (size_t)(R0 + trow) * (size_t)t_stride + l31;
#pragma unroll
        for (int ct = 0; ct < 4; ++ct) rp[ct * 32] = (f16)o[ct][r];
    }
    __syncthreads();   // b2: all Yf/Vf reads done

    float* SS = (float*)(smem + AD_OFF_Y);   // [2][8][128]
    if (hl == 0) {
#pragma unroll
        for (int ct = 0; ct < 4; ++ct) {
            SS[w * 128 + ct * 32 + l31] = ssa[ct];
            SS[1024 + w * 128 + ct * 32 + l31] = sqa[ct];
        }
    }
    __syncthreads();   // b3
    if (tid < 256) {
        int c = tid & 127, which = tid >> 7;
        float acc = 0.f;
#pragma unroll
        for (int iw = 0; iw < 8; ++iw) acc += SS[which * 1024 + iw * 128 + c];
        atomicAdd(&gstats[which * 128 + c], acc);
    }
}

// =====================================================================================
// final: U2 f16 [b][n1][n2][c] -> BN2+ReLU -> out fp32 [B,C,H,W], f32x4 stores.
// BN2 (a,b) computed per block from raw gstats (no separate bnfix kernel).
// =====================================================================================
__global__ __launch_bounds__(256) void final_kernel(const f16* __restrict__ U2,
                                                    const float* __restrict__ gst,
                                                    const float* __restrict__ gamma,
                                                    const float* __restrict__ beta,
                                                    float* __restrict__ out) {
    __shared__ f16 L[256 * 132];      // [n2][c] padded
    __shared__ float AB[256];
    const int tid = threadIdx.x, g = blockIdx.x;
    const int b = g >> 8, i1 = (g >> 4) & 15, j1 = g & 15;
    if (tid < 128) {
        const float inv = 1.f / 262144.f;
        float mean = gst[tid] * inv;
        float var = gst[128 + tid] * inv - mean * mean;
        float a = gamma[tid] * rsqrtf(var + 1e-5f);
        AB[tid] = a;
        AB[128 + tid] = beta[tid] - mean * a;
    }
    const f16* src = U2 + (size_t)g * 32768;
#pragma unroll
    for (int e = 0; e < 16; ++e) {
        int u = e * 2048 + tid * 8;
        int row = u >> 7, c0 = u & 127;
        f16x8 v = *(const f16x8*)(src + u);
        f16* dst = L + row * 132 + c0;
        *(f16x4*)dst = lo4(v);
        *(f16x4*)(dst + 4) = hi4(v);
    }
    __syncthreads();
    const int j2q = tid & 3, u0 = tid >> 2;
#pragma unroll 4
    for (int k = 0; k < 32; ++k) {
        int unit = u0 + k * 64;        // 0..2047 -> (c, i2)
        int c = unit & 127, i2 = unit >> 7;
        float a = AB[c], bb = AB[128 + c];
        f32x4 vv;
#pragma unroll
        for (int jj = 0; jj < 4; ++jj)
            vv[jj] = fmaxf(a * (float)L[(i2 * 16 + j2q * 4 + jj) * 132 + c] + bb, 0.f);
        *(f32x4*)(out + (((size_t)b * 128 + c) * 256 + i1 * 16 + i2) * 256 + j1 * 16 + j2q * 4) =
            vv;
    }
}

// =====================================================================================
extern "C" void kernel_launch(void* const* d_in, const int* in_sizes, int n_in, void* d_out,
                              int out_size, void* d_ws, size_t ws_size, hipStream_t stream) {
    (void)in_sizes; (void)n_in; (void)out_size; (void)ws_size;
    const float* x = (const float*)d_in[0];
    const float* w1x = (const float*)d_in[1];
    const float* b1x = (const float*)d_in[2];
    const float* w1y = (const float*)d_in[3];
    const float* b1y = (const float*)d_in[4];
    const float* w1o = (const float*)d_in[5];
    const float* b1o = (const float*)d_in[6];
    const float* g1 = (const float*)d_in[7];
    const float* be1 = (const float*)d_in[8];
    const float* w2x = (const float*)d_in[9];
    const float* b2x = (const float*)d_in[10];
    const float* w2y = (const float*)d_in[11];
    const float* b2y = (const float*)d_in[12];
    const float* w2o = (const float*)d_in[13];
    const float* b2o = (const float*)d_in[14];
    const float* g2 = (const float*)d_in[15];
    const float* be2 = (const float*)d_in[16];

    // d_out doubles as scratch: [0,64MiB) Xall f16, [64MiB,128MiB) U1 f16 (both dead
    // before final_kernel rewrites d_out as fp32).
    f16* Xall = (f16*)d_out;
    f16* U1 = (f16*)((char*)d_out + 67108864);
    f16* U2 = (f16*)d_ws;
    f16* Wbf = (f16*)((char*)d_ws + 67108864);                  // [2][WSTRIDE] f16
    float* gstats = (float*)((char*)d_ws + 67108864 + 262144);  // [2][256]

    wconv_kernel<<<259, 256, 0, stream>>>(w1x, w1y, w1o, b1x, b1y, w2x, w2y, w2o, b2x, b2y, Wbf,
                                          gstats);
    repack_kernel<<<1024, 512, 0, stream>>>(x, Xall);

    attd_kernel<1><<<1024, 512, 0, stream>>>(Xall, Wbf, b1o, (const float*)nullptr,
                                             (const float*)nullptr, (const float*)nullptr, U1,
                                             gstats, 32768, 128);
    attd_kernel<2><<<1024, 512, 0, stream>>>(U1, Wbf + WSTRIDE, b2o, gstats, g1, be1, U2,
                                             gstats + 256, 128, 32768);
    final_kernel<<<1024, 256, 0, stream>>>(U2, gstats + 256, g2, be2, (float*)d_out);
}

// Round 15
// 252.293 us; speedup vs baseline: 1.0405x; 1.0405x over previous
//
#include <hip/hip_runtime.h>

typedef _Float16 f16;
typedef f16 f16x2 __attribute__((ext_vector_type(2)));
typedef f16 f16x4 __attribute__((ext_vector_type(4)));
typedef f16 f16x8 __attribute__((ext_vector_type(8)));
typedef float f32x4 __attribute__((ext_vector_type(4)));
typedef float f32x16 __attribute__((ext_vector_type(16)));
typedef unsigned int u32;
typedef u32 u32x2 __attribute__((ext_vector_type(2)));
typedef u32 u32x4 __attribute__((ext_vector_type(4)));

#define MFMA32(a, b, c) __builtin_amdgcn_mfma_f32_32x32x16_f16((a), (b), (c), 0, 0, 0)

__device__ __forceinline__ u32 pk2(float a, float b) {
    return __builtin_bit_cast(u32, __builtin_amdgcn_cvt_pkrtz(a, b));
}
__device__ __forceinline__ f16x4 lo4(f16x8 v) { return __builtin_shufflevector(v, v, 0, 1, 2, 3); }
__device__ __forceinline__ f16x4 hi4(f16x8 v) { return __builtin_shufflevector(v, v, 4, 5, 6, 7); }

// C-frag (rows in regs, col on lanes) -> A/B-frag (same lane, 8 consecutive rows as elems).
__device__ __forceinline__ f16x8 xfrm(f32x16 v, int rb) {
    u32 a0 = pk2(v[rb + 0], v[rb + 1]);
    u32 a1 = pk2(v[rb + 2], v[rb + 3]);
    u32 b0 = pk2(v[rb + 4], v[rb + 5]);
    u32 b1 = pk2(v[rb + 6], v[rb + 7]);
    u32x2 r0 = __builtin_amdgcn_permlane32_swap(a0, b0, false, false);
    u32x2 r1 = __builtin_amdgcn_permlane32_swap(a1, b1, false, false);
    u32x4 aw = {r0.x, r1.x, r0.y, r1.y};
    return __builtin_bit_cast(f16x8, aw);
}
__device__ __forceinline__ f16x8 add8(f16x8 a, f16x8 b) {
    f16x8 r;
#pragma unroll
    for (int j = 0; j < 8; ++j) r[j] = a[j] + b[j];
    return r;
}

// disjoint-LDS attention kernel regions -------------------------------------
#define AD_OFF_Y 65536
#define AD_OFF_V 98304
#define AD_LDS   163840

// per-pass Wf stride in f16: 32768 W + 128 bias (bq f16[64], bk f16[64])
#define WSTRIDE 32896

// =====================================================================================
// repack: x fp32 [B,C,H,W] -> Xall f16 [b][n2=(i2,j2)][n1=(i1,j1)][c]
// =====================================================================================
__global__ __launch_bounds__(512) void repack_kernel(const float* __restrict__ x,
                                                     f16* __restrict__ Xall) {
    __shared__ f16 XT[128 * 264];     // [c][w], padded
    const int tid = threadIdx.x, g = blockIdx.x;
    const int b = g >> 8, i1 = (g >> 4) & 15, i2 = g & 15;
    const int h = i1 * 16 + i2;
    {
        const int c = tid >> 2, wq = (tid & 3) * 64;
        const float* src = x + (((size_t)b * 128 + c) * 256 + h) * 256 + wq;
        f16* dst = XT + c * 264 + wq;
#pragma unroll
        for (int i = 0; i < 16; ++i) {
            f32x4 v = *(const f32x4*)(src + i * 4);
            f16x4 o = {(f16)v[0], (f16)v[1], (f16)v[2], (f16)v[3]};
            *(f16x4*)(dst + i * 4) = o;
        }
    }
    __syncthreads();
    {
        const int w = tid >> 1, ch = (tid & 1) * 64;   // w = j1*16 + j2
        const int j1 = w >> 4, j2 = w & 15;
        f16* dst = Xall + (((size_t)b * 256 + i2 * 16 + j2) * 256 + i1 * 16 + j1) * 128 + ch;
#pragma unroll
        for (int i = 0; i < 8; ++i) {
            f16x8 v;
#pragma unroll
            for (int j = 0; j < 8; ++j) v[j] = XT[(ch + i * 8 + j) * 264 + w];
            *(f16x8*)(dst + i * 8) = v;
        }
    }
}

// =====================================================================================
// weight conversion fp32 -> f16 (fragment-linear + f16 bias tail) + gstats zeroing
// =====================================================================================
__global__ void wconv_kernel(const float* __restrict__ w1x, const float* __restrict__ w1y,
                             const float* __restrict__ w1o, const float* __restrict__ b1x,
                             const float* __restrict__ b1y, const float* __restrict__ w2x,
                             const float* __restrict__ w2y, const float* __restrict__ w2o,
                             const float* __restrict__ b2x, const float* __restrict__ b2y,
                             f16* __restrict__ Wf, float* __restrict__ gstats) {
    int i = blockIdx.x * 256 + threadIdx.x;      // 66304 total
    if (i < 65536) {
        int p = i >> 15, idx = i & 32767;
        int j = idx & 7, lane = (idx >> 3) & 63, ks = (idx >> 9) & 7, r = idx >> 12;
        int row = r * 32 + (lane & 31);
        int c = ks * 16 + (lane >> 5) * 8 + j;
        const float* s;
        if (p == 0) s = (row < 128) ? w1o + row * 128 : (row < 192) ? w1x + (row - 128) * 128
                                                                   : w1y + (row - 192) * 128;
        else        s = (row < 128) ? w2o + row * 128 : (row < 192) ? w2x + (row - 128) * 128
                                                                   : w2y + (row - 192) * 128;
        Wf[p * WSTRIDE + idx] = (f16)s[c];
    } else if (i < 65792) {
        int idx2 = i - 65536;                    // 0..255
        int p = idx2 >> 7, r = idx2 & 127;
        const float* bsrc = (p == 0) ? ((r < 64) ? b1x : b1y) : ((r < 64) ? b2x : b2y);
        Wf[p * WSTRIDE + 32768 + r] = (f16)bsrc[r & 63];
    } else {
        gstats[i - 65792] = 0.f;                 // [2][256] stats cleared
    }
}

// =====================================================================================
// attd: disjoint-LDS fused attention, both passes.
//   out = softmax(theta psi) @ (X Wo^T + bo)
// W(64K) + Yf(32K) + Vf(64K) disjoint; register BN-stats.
// PASS2 applies precomputed BN1 (a,b) from bnab (bnfix kernel output).
// =====================================================================================
template <int PASS>
__global__ __launch_bounds__(512, 2) void attd_kernel(
    const f16* __restrict__ Xin, const f16* __restrict__ Wf, const float* __restrict__ bo,
    const float* __restrict__ bnab, f16* __restrict__ Uout, float* __restrict__ gstats,
    int t_stride, int s_stride) {
    __shared__ __align__(16) char smem[AD_LDS];
    const int tid = threadIdx.x;
    const int w = tid >> 6, l = tid & 63, hl = l >> 5, l31 = l & 31;
    const int g = blockIdx.x, R0 = w * 32;

    const f16* bfp = Wf + 32768;
    f16x8 bqf[4], bkf[4];
#pragma unroll
    for (int ks = 0; ks < 4; ++ks) {
        bqf[ks] = *(const f16x8*)(bfp + ks * 16 + hl * 8);
        bkf[ks] = *(const f16x8*)(bfp + 64 + ks * 16 + hl * 8);
    }
    float bov[4];
#pragma unroll
    for (int ct = 0; ct < 4; ++ct) bov[ct] = bo[ct * 32 + l31];

    // ---- prologue: W -> LDS, X -> afr (loads overlap); PASS2: BN1+ReLU via bnab ----
    f16x8 afr[8];
    {
        f16x8 wv[8];
#pragma unroll
        for (int j = 0; j < 8; ++j)
            wv[j] = *(const f16x8*)((const char*)Wf + (j * 512 + tid) * 16);
        const f16* src = Xin + (size_t)g * 32768 + (R0 + l31) * 128 + hl * 8;
#pragma unroll
        for (int ks = 0; ks < 8; ++ks) afr[ks] = *(const f16x8*)(src + ks * 16);
        if constexpr (PASS == 2) {
#pragma unroll
            for (int ks = 0; ks < 8; ++ks) {
                const int c0 = ks * 16 + hl * 8;
                f32x4 a0 = *(const f32x4*)(bnab + c0), a1 = *(const f32x4*)(bnab + c0 + 4);
                f32x4 s0 = *(const f32x4*)(bnab + 128 + c0), s1 = *(const f32x4*)(bnab + 132 + c0);
                f16x8 v = afr[ks];
#pragma unroll
                for (int j = 0; j < 4; ++j) {
                    v[j]     = (f16)fmaxf(a0[j] * (float)v[j]     + s0[j], 0.f);
                    v[j + 4] = (f16)fmaxf(a1[j] * (float)v[j + 4] + s1[j], 0.f);
                }
                afr[ks] = v;
            }
        }
#pragma unroll
        for (int j = 0; j < 8; ++j)
            *(f16x8*)(smem + (j * 512 + tid) * 16) = wv[j];
    }
    __syncthreads();   // b0: W resident

    // ---- psi^T (tiles 6-7) -> Yf ----
    {
        f32x16 aP[2] = {};
#pragma unroll
        for (int ks = 0; ks < 8; ++ks)
#pragma unroll
            for (int mt = 0; mt < 2; ++mt) {
                f16x8 wk = *(const f16x8*)(smem + (((6 + mt) * 8 + ks) * 64 + l) * 16);
                aP[mt] = MFMA32(wk, afr[ks], aP[mt]);
            }
#pragma unroll
        for (int ks = 0; ks < 4; ++ks) {
            f16x8 yf = add8(xfrm(aP[ks >> 1], 8 * (ks & 1)), bkf[ks]);
            *(f16x8*)(smem + AD_OFF_Y + ((w * 4 + ks) * 64 + l) * 16) = yf;
        }
    }

    // ---- theta^T (tiles 4-5) -> tb in-register ----
    f16x8 tb[4];
    {
        f32x16 aT[2] = {};
#pragma unroll
        for (int ks = 0; ks < 8; ++ks)
#pragma unroll
            for (int mt = 0; mt < 2; ++mt) {
                f16x8 wq = *(const f16x8*)(smem + (((4 + mt) * 8 + ks) * 64 + l) * 16);
                aT[mt] = MFMA32(wq, afr[ks], aT[mt]);
            }
#pragma unroll
        for (int ks = 0; ks < 4; ++ks)
            tb[ks] = add8(xfrm(aT[ks >> 1], 8 * (ks & 1)), bqf[ks]);
    }

    // ---- V'' (tiles 0-3) -> pack -> Vf ----
    {
        f32x16 aV[4] = {};
#pragma unroll
        for (int ks = 0; ks < 8; ++ks)
#pragma unroll
            for (int ct = 0; ct < 4; ++ct) {
                f16x8 wo = *(const f16x8*)(smem + ((ct * 8 + ks) * 64 + l) * 16);
                aV[ct] = MFMA32(afr[ks], wo, aV[ct]);
            }
#pragma unroll
        for (int ct = 0; ct < 4; ++ct) {
#pragma unroll
            for (int e = 0; e < 16; ++e) aV[ct][e] += bov[ct];
#pragma unroll
            for (int ksl = 0; ksl < 2; ++ksl)
                *(f16x8*)(smem + AD_OFF_V + (((2 * w + ksl) * 4 + ct) * 64 + l) * 16) =
                    xfrm(aV[ct], 8 * ksl);
        }
    }
    __syncthreads();   // b1: Yf + Vf complete

    // ---- S^T: col t = R0+l31 on lanes, all 256 k rows in regs ----
    f32x16 s[8] = {};
    __builtin_amdgcn_s_setprio(1);
#pragma unroll
    for (int kt = 0; kt < 8; ++kt)
#pragma unroll
        for (int ks = 0; ks < 4; ++ks) {
            f16x8 ay = *(const f16x8*)(smem + AD_OFF_Y + ((kt * 4 + ks) * 64 + l) * 16);
            s[kt] = MFMA32(ay, tb[ks], s[kt]);
        }
    __builtin_amdgcn_s_setprio(0);

    // ---- softmax over k ----
    float mx = -1e30f;
#pragma unroll
    for (int kt = 0; kt < 8; ++kt) {
        float m0 = fmaxf(fmaxf(s[kt][0], s[kt][1]), fmaxf(s[kt][2], s[kt][3]));
        float m1 = fmaxf(fmaxf(s[kt][4], s[kt][5]), fmaxf(s[kt][6], s[kt][7]));
        float m2 = fmaxf(fmaxf(s[kt][8], s[kt][9]), fmaxf(s[kt][10], s[kt][11]));
        float m3 = fmaxf(fmaxf(s[kt][12], s[kt][13]), fmaxf(s[kt][14], s[kt][15]));
        mx = fmaxf(mx, fmaxf(fmaxf(m0, m1), fmaxf(m2, m3)));
    }
    mx = fmaxf(mx, __shfl_xor(mx, 32));
    float sum = 0.f;
#pragma unroll
    for (int kt = 0; kt < 8; ++kt)
#pragma unroll
        for (int e = 0; e < 16; ++e) {
            float p = __expf(s[kt][e] - mx);
            s[kt][e] = p;
            sum += p;
        }
    sum += __shfl_xor(sum, 32);
    const float rs = 1.f / sum;
#pragma unroll
    for (int kt = 0; kt < 8; ++kt)
#pragma unroll
        for (int e = 0; e < 16; ++e) s[kt][e] *= rs;

    // ---- PV: A-frags in-register (xfrm), B from Vf ----
    f32x16 o[4] = {};
#pragma unroll
    for (int kt = 0; kt < 8; ++kt)
#pragma unroll
        for (int ks2 = 0; ks2 < 2; ++ks2) {
            f16x8 ap = xfrm(s[kt], 8 * ks2);
            __builtin_amdgcn_s_setprio(1);
#pragma unroll
            for (int ct = 0; ct < 4; ++ct) {
                f16x8 bv =
                    *(const f16x8*)(smem + AD_OFF_V + (((kt * 2 + ks2) * 4 + ct) * 64 + l) * 16);
                o[ct] = MFMA32(ap, bv, o[ct]);
            }
            __builtin_amdgcn_s_setprio(0);
        }

    // ---- BN stats (registers) + stores ----
    float ssa[4], sqa[4];
#pragma unroll
    for (int ct = 0; ct < 4; ++ct) {
        float ss = 0.f, sq = 0.f;
#pragma unroll
        for (int e = 0; e < 16; ++e) {
            float v = o[ct][e];
            ss += v;
            sq += v * v;
        }
        ssa[ct] = ss + __shfl_xor(ss, 32);
        sqa[ct] = sq + __shfl_xor(sq, 32);
    }
    const size_t ub = (size_t)(g >> 8) * 8388608 + (size_t)(g & 255) * (size_t)s_stride;
#pragma unroll
    for (int r = 0; r < 16; ++r) {
        int trow = (r & 3) + 8 * (r >> 2) + 4 * hl;
        f16* rp = Uout + ub + (size_t)(R0 + trow) * (size_t)t_stride + l31;
#pragma unroll
        for (int ct = 0; ct < 4; ++ct) rp[ct * 32] = (f16)o[ct][r];
    }
    __syncthreads();   // b2: all Yf/Vf reads done

    float* SS = (float*)(smem + AD_OFF_Y);   // [2][8][128]
    if (hl == 0) {
#pragma unroll
        for (int ct = 0; ct < 4; ++ct) {
            SS[w * 128 + ct * 32 + l31] = ssa[ct];
            SS[1024 + w * 128 + ct * 32 + l31] = sqa[ct];
        }
    }
    __syncthreads();   // b3
    if (tid < 256) {
        int c = tid & 127, which = tid >> 7;
        float acc = 0.f;
#pragma unroll
        for (int iw = 0; iw < 8; ++iw) acc += SS[which * 1024 + iw * 128 + c];
        atomicAdd(&gstats[which * 128 + c], acc);
    }
}

// =====================================================================================
// BN stats finalize: (sum, sumsq) -> (a, b) with y = a*x + b
// =====================================================================================
__global__ void bnfix_kernel(const float* __restrict__ gstats, const float* __restrict__ gamma,
                             const float* __restrict__ beta, float* __restrict__ ab) {
    int c = threadIdx.x;
    if (c < 128) {
        const float inv = 1.f / 262144.f;
        float mean = gstats[c] * inv;
        float var = gstats[128 + c] * inv - mean * mean;
        float rstd = rsqrtf(var + 1e-5f);
        float a = gamma[c] * rstd;
        ab[c] = a;
        ab[128 + c] = beta[c] - mean * a;
    }
}

// =====================================================================================
// final: U2 f16 [b][n1][n2][c] -> BN2+ReLU -> out fp32 [B,C,H,W], f32x4 stores.
// BN2 (a,b) computed per block from raw gstats (off critical path, one rsqrt/thread).
// =====================================================================================
__global__ __launch_bounds__(256) void final_kernel(const f16* __restrict__ U2,
                                                    const float* __restrict__ gst,
                                                    const float* __restrict__ gamma,
                                                    const float* __restrict__ beta,
                                                    float* __restrict__ out) {
    __shared__ f16 L[256 * 132];      // [n2][c] padded
    __shared__ float AB[256];
    const int tid = threadIdx.x, g = blockIdx.x;
    const int b = g >> 8, i1 = (g >> 4) & 15, j1 = g & 15;
    if (tid < 128) {
        const float inv = 1.f / 262144.f;
        float mean = gst[tid] * inv;
        float var = gst[128 + tid] * inv - mean * mean;
        float a = gamma[tid] * rsqrtf(var + 1e-5f);
        AB[tid] = a;
        AB[128 + tid] = beta[tid] - mean * a;
    }
    const f16* src = U2 + (size_t)g * 32768;
#pragma unroll
    for (int e = 0; e < 16; ++e) {
        int u = e * 2048 + tid * 8;
        int row = u >> 7, c0 = u & 127;
        f16x8 v = *(const f16x8*)(src + u);
        f16* dst = L + row * 132 + c0;
        *(f16x4*)dst = lo4(v);
        *(f16x4*)(dst + 4) = hi4(v);
    }
    __syncthreads();
    const int j2q = tid & 3, u0 = tid >> 2;
#pragma unroll 4
    for (int k = 0; k < 32; ++k) {
        int unit = u0 + k * 64;        // 0..2047 -> (c, i2)
        int c = unit & 127, i2 = unit >> 7;
        float a = AB[c], bb = AB[128 + c];
        f32x4 vv;
#pragma unroll
        for (int jj = 0; jj < 4; ++jj)
            vv[jj] = fmaxf(a * (float)L[(i2 * 16 + j2q * 4 + jj) * 132 + c] + bb, 0.f);
        *(f32x4*)(out + (((size_t)b * 128 + c) * 256 + i1 * 16 + i2) * 256 + j1 * 16 + j2q * 4) =
            vv;
    }
}

// =====================================================================================
extern "C" void kernel_launch(void* const* d_in, const int* in_sizes, int n_in, void* d_out,
                              int out_size, void* d_ws, size_t ws_size, hipStream_t stream) {
    (void)in_sizes; (void)n_in; (void)out_size; (void)ws_size;
    const float* x = (const float*)d_in[0];
    const float* w1x = (const float*)d_in[1];
    const float* b1x = (const float*)d_in[2];
    const float* w1y = (const float*)d_in[3];
    const float* b1y = (const float*)d_in[4];
    const float* w1o = (const float*)d_in[5];
    const float* b1o = (const float*)d_in[6];
    const float* g1 = (const float*)d_in[7];
    const float* be1 = (const float*)d_in[8];
    const float* w2x = (const float*)d_in[9];
    const float* b2x = (const float*)d_in[10];
    const float* w2y = (const float*)d_in[11];
    const float* b2y = (const float*)d_in[12];
    const float* w2o = (const float*)d_in[13];
    const float* b2o = (const float*)d_in[14];
    const float* g2 = (const float*)d_in[15];
    const float* be2 = (const float*)d_in[16];

    // d_out doubles as scratch: [0,64MiB) Xall f16, [64MiB,128MiB) U1 f16 (both dead
    // before final_kernel rewrites d_out as fp32).
    f16* Xall = (f16*)d_out;
    f16* U1 = (f16*)((char*)d_out + 67108864);
    f16* U2 = (f16*)d_ws;
    f16* Wbf = (f16*)((char*)d_ws + 67108864);                  // [2][WSTRIDE] f16
    float* gstats = (float*)((char*)d_ws + 67108864 + 262144);  // [2][256]
    float* bnab = gstats + 512;                                 // [256] pass-1 (a,b)

    wconv_kernel<<<259, 256, 0, stream>>>(w1x, w1y, w1o, b1x, b1y, w2x, w2y, w2o, b2x, b2y, Wbf,
                                          gstats);
    repack_kernel<<<1024, 512, 0, stream>>>(x, Xall);

    attd_kernel<1><<<1024, 512, 0, stream>>>(Xall, Wbf, b1o, (const float*)nullptr, U1, gstats,
                                             32768, 128);
    bnfix_kernel<<<1, 128, 0, stream>>>(gstats, g1, be1, bnab);
    attd_kernel<2><<<1024, 512, 0, stream>>>(U1, Wbf + WSTRIDE, b2o, bnab, U2, gstats + 256, 128,
                                             32768);
    final_kernel<<<1024, 256, 0, stream>>>(U2, gstats + 256, g2, be2, (float*)d_out);
}